// Round 7
// baseline (65.690 us; speedup 1.0000x reference)
//
#include <hip/hip_runtime.h>
#include <hip/hip_bf16.h>

// MaskNet edge scorer (2 kernels):
//   k1 (node_proj): per-block w1 -> LDS fragment table, then
//       y1[n] = W1[:, :128] @ x[n] + b1 ; y2[n] = W1[:, 128:] @ x[n]
//       ytab[n] = [y1 | y2] bf16  (12.8 MB in d_ws)
//   k2 (edge): s[e] = sigmoid( w2 . relu(y1[row] + y2[col]) + b2 )
// Edge phase is pinned at the L2-miss-path ceiling (~3.5 TB/s on ~147 MB of
// 128 B random-gather misses; ~115 MB is compulsory per-XCD table traffic).

typedef __attribute__((ext_vector_type(8))) short bf16x8;
typedef __attribute__((ext_vector_type(4))) float f32x4;
typedef __attribute__((ext_vector_type(4))) int   i32x4;
typedef __attribute__((ext_vector_type(4))) unsigned short u16x4;

#define IN_DIM 128
#define HIDDEN 64

// native f32 -> bf16 (compiler emits v_cvt_pk_bf16_f32 for pairs, RNE)
__device__ __forceinline__ unsigned short bfbits(float f) {
    __hip_bfloat16 h = __float2bfloat16(f);
    return __builtin_bit_cast(unsigned short, h);
}

__device__ __forceinline__ bf16x8 pack8(const float4& lo, const float4& hi) {
    bf16x8 b;
    b[0] = (short)bfbits(lo.x); b[1] = (short)bfbits(lo.y);
    b[2] = (short)bfbits(lo.z); b[3] = (short)bfbits(lo.w);
    b[4] = (short)bfbits(hi.x); b[5] = (short)bfbits(hi.y);
    b[6] = (short)bfbits(hi.z); b[7] = (short)bfbits(hi.w);
    return b;
}

// ---------------- node projection (w1 conversion fused as prologue) ----------------
// One wave per 16-node tile. MFMA 16x16x32 bf16, A = weights (LDS), B = node x:
//   A[m][k]: lane m=l&15 (dim within 16-block), k=8*(l>>4)+i
//   B[k][n]: lane n=l&15 (node), same k
//   D: col=l&15 (node), row=4*(l>>4)+reg (dim) -> lane owns one node,
//      4 consecutive dims per dt -> 8 B stores.
__global__ __launch_bounds__(256) void node_proj_kernel(
    const float* __restrict__ x,          // [N][128]
    const float* __restrict__ w1,         // [64][256]
    const float* __restrict__ b1,         // [64]
    unsigned short* __restrict__ ytab,    // [N][128] bf16 bits
    int N, int ntiles)
{
    __shared__ short wfrag[2048 * 8];   // 32 KB: [dt*4+kk][lane][8]

    // prologue: convert w1 -> LDS fragment table. Thread v handles w1 flat
    // floats [v*64, v*64+64) — contiguous 256 B global reads per thread.
    {
        int v = threadIdx.x;
#pragma unroll
        for (int j = 0; j < 8; ++j) {
            int f = v * 64 + j * 8;          // flat index into w1 (64*256)
            int r = f >> 8;                  // w1 row (0..63)
            int k = f & 255;                 // col in [0,256)
            float4 lo = *(const float4*)(w1 + f);
            float4 hi = *(const float4*)(w1 + f + 4);
            int o, kk, g;
            if (k < IN_DIM) { o = r;          kk = k >> 5;             g = (k & 31) >> 3; }
            else            { o = r + HIDDEN; kk = (k - IN_DIM) >> 5;  g = ((k - IN_DIM) & 31) >> 3; }
            int dt = o >> 4, m = o & 15;
            int lane = g * 16 + m;
            *(bf16x8*)&wfrag[((dt * 4 + kk) * 64 + lane) * 8] = pack8(lo, hi);
        }
    }
    __syncthreads();

    int wave = (int)((blockIdx.x * blockDim.x + threadIdx.x) >> 6);
    if (wave >= ntiles) return;

    int lane = threadIdx.x & 63;
    int m = lane & 15;       // node offset within tile
    int g = lane >> 4;       // k-group / dim subgroup
    int n0 = wave * 16;

    int node = n0 + m;
    bool valid = node < N;
    int nc = valid ? node : N - 1;
    const float* xr = x + (size_t)nc * IN_DIM;

    bf16x8 xf[4];
#pragma unroll
    for (int kk = 0; kk < 4; ++kk) {
        int k0 = kk * 32 + g * 8;
        float4 lo = *(const float4*)(xr + k0);
        float4 hi = *(const float4*)(xr + k0 + 4);
        xf[kk] = pack8(lo, hi);
    }

    f32x4 acc[8] = {};
#pragma unroll
    for (int dt = 0; dt < 8; ++dt) {
#pragma unroll
        for (int kk = 0; kk < 4; ++kk) {
            bf16x8 wf = *(const bf16x8*)&wfrag[((dt * 4 + kk) * 64 + lane) * 8];
            acc[dt] = __builtin_amdgcn_mfma_f32_16x16x32_bf16(wf, xf[kk], acc[dt], 0, 0, 0);
        }
    }

    if (valid) {
        unsigned short* yrow = ytab + (size_t)node * IN_DIM;
#pragma unroll
        for (int dt = 0; dt < 8; ++dt) {
            float4 b4;
            if (dt < 4) b4 = *(const float4*)(b1 + dt * 16 + g * 4);
            else        b4 = make_float4(0.f, 0.f, 0.f, 0.f);
            u16x4 s;
            s[0] = bfbits(acc[dt][0] + b4.x);
            s[1] = bfbits(acc[dt][1] + b4.y);
            s[2] = bfbits(acc[dt][2] + b4.z);
            s[3] = bfbits(acc[dt][3] + b4.w);
            *(u16x4*)(yrow + dt * 16 + g * 4) = s;
        }
    }
}

// ---------------- edge kernel: 8 lanes per edge, 8 edges per group ----------------
__device__ __forceinline__ float dimpair(unsigned u1, unsigned u2, float wlo, float whi, float acc) {
    float a0 = __uint_as_float(u1 << 16);
    float a1 = __uint_as_float(u1 & 0xffff0000u);
    float b0 = __uint_as_float(u2 << 16);
    float b1v = __uint_as_float(u2 & 0xffff0000u);
    float h0 = fmaxf(a0 + b0, 0.f);
    float h1 = fmaxf(a1 + b1v, 0.f);
    acc = fmaf(h0, wlo, acc);
    acc = fmaf(h1, whi, acc);
    return acc;
}

__device__ __forceinline__ float edge_dot(const uint4& ua, const uint4& ub,
                                          const float4& w2a, const float4& w2b) {
    float acc = 0.f;
    acc = dimpair(ua.x, ub.x, w2a.x, w2a.y, acc);
    acc = dimpair(ua.y, ub.y, w2a.z, w2a.w, acc);
    acc = dimpair(ua.z, ub.z, w2b.x, w2b.y, acc);
    acc = dimpair(ua.w, ub.w, w2b.z, w2b.w, acc);
    acc += __shfl_xor(acc, 1);
    acc += __shfl_xor(acc, 2);
    acc += __shfl_xor(acc, 4);
    return acc;
}

__device__ __forceinline__ float sigmoidf(float z) {
    return 1.f / (1.f + __expf(-z));
}

__global__ __launch_bounds__(256) void edge_kernel(
    const int* __restrict__ ei,                 // [2][E] int32
    const unsigned short* __restrict__ ytab,    // [N][128] bf16 bits
    const float* __restrict__ w2,               // [64]
    const float* __restrict__ b2,               // [1]
    float* __restrict__ out,                    // [E]
    int E)
{
    int t = (int)(blockIdx.x * 256 + threadIdx.x);
    int q = t >> 3;          // edge-octet id
    int sub = t & 7;
    int e0 = q * 8;
    if (e0 >= E) return;

    const char* yb = (const char*)ytab;
    float4 w2a = *((const float4*)w2 + sub * 2);
    float4 w2b = *((const float4*)w2 + sub * 2 + 1);
    int so = sub << 4;

    if (e0 + 8 <= E) {
        // streaming index reads: non-temporal (read-once; don't pollute L2,
        // keep capacity for ytab gather lines). ext_vector ptrs for the builtin.
        i32x4 ra = __builtin_nontemporal_load((const i32x4*)(ei + e0));
        i32x4 rb = __builtin_nontemporal_load((const i32x4*)(ei + e0 + 4));
        i32x4 ca = __builtin_nontemporal_load((const i32x4*)(ei + E + e0));
        i32x4 cb = __builtin_nontemporal_load((const i32x4*)(ei + E + e0 + 4));
        // issue all 16 gathers before any use (latency overlap)
        uint4 a0 = *(const uint4*)(yb + ((ra[0] << 8) + so));
        uint4 a1 = *(const uint4*)(yb + ((ra[1] << 8) + so));
        uint4 a2 = *(const uint4*)(yb + ((ra[2] << 8) + so));
        uint4 a3 = *(const uint4*)(yb + ((ra[3] << 8) + so));
        uint4 a4 = *(const uint4*)(yb + ((rb[0] << 8) + so));
        uint4 a5 = *(const uint4*)(yb + ((rb[1] << 8) + so));
        uint4 a6 = *(const uint4*)(yb + ((rb[2] << 8) + so));
        uint4 a7 = *(const uint4*)(yb + ((rb[3] << 8) + so));
        uint4 c0 = *(const uint4*)(yb + ((ca[0] << 8) + 128 + so));
        uint4 c1 = *(const uint4*)(yb + ((ca[1] << 8) + 128 + so));
        uint4 c2 = *(const uint4*)(yb + ((ca[2] << 8) + 128 + so));
        uint4 c3 = *(const uint4*)(yb + ((ca[3] << 8) + 128 + so));
        uint4 c4 = *(const uint4*)(yb + ((cb[0] << 8) + 128 + so));
        uint4 c5 = *(const uint4*)(yb + ((cb[1] << 8) + 128 + so));
        uint4 c6 = *(const uint4*)(yb + ((cb[2] << 8) + 128 + so));
        uint4 c7 = *(const uint4*)(yb + ((cb[3] << 8) + 128 + so));

        float z0 = edge_dot(a0, c0, w2a, w2b);
        float z1 = edge_dot(a1, c1, w2a, w2b);
        float z2 = edge_dot(a2, c2, w2a, w2b);
        float z3 = edge_dot(a3, c3, w2a, w2b);
        float z4 = edge_dot(a4, c4, w2a, w2b);
        float z5 = edge_dot(a5, c5, w2a, w2b);
        float z6 = edge_dot(a6, c6, w2a, w2b);
        float z7 = edge_dot(a7, c7, w2a, w2b);

        if (sub == 0) {
            float bb = b2[0];
            f32x4 s0, s1;
            s0[0] = sigmoidf(z0 + bb);
            s0[1] = sigmoidf(z1 + bb);
            s0[2] = sigmoidf(z2 + bb);
            s0[3] = sigmoidf(z3 + bb);
            s1[0] = sigmoidf(z4 + bb);
            s1[1] = sigmoidf(z5 + bb);
            s1[2] = sigmoidf(z6 + bb);
            s1[3] = sigmoidf(z7 + bb);
            // write-once stream: non-temporal stores
            __builtin_nontemporal_store(s0, (f32x4*)(out + e0));
            __builtin_nontemporal_store(s1, (f32x4*)(out + e0 + 4));
        }
    } else {
        float bb = b2[0];
        for (int e = e0; e < E; ++e) {
            int row = ei[e];
            int col = ei[E + e];
            uint4 ua = *(const uint4*)(yb + ((row << 8) + so));
            uint4 ub = *(const uint4*)(yb + ((col << 8) + 128 + so));
            float z = edge_dot(ua, ub, w2a, w2b);
            if (sub == 0) out[e] = sigmoidf(z + bb);
        }
    }
}

extern "C" void kernel_launch(void* const* d_in, const int* in_sizes, int n_in,
                              void* d_out, int out_size, void* d_ws, size_t ws_size,
                              hipStream_t stream) {
    const float* x  = (const float*)d_in[0];
    const int*   ei = (const int*)d_in[1];
    const float* w1 = (const float*)d_in[2];
    const float* b1 = (const float*)d_in[3];
    const float* w2 = (const float*)d_in[4];
    const float* b2 = (const float*)d_in[5];
    float* out = (float*)d_out;

    int N = in_sizes[0] / IN_DIM;
    int E = in_sizes[1] / 2;

    unsigned short* ytab = (unsigned short*)d_ws;  // [N][128] bf16 = 12.8 MB

    int ntiles = (N + 15) / 16;
    int nblocks = (ntiles + 3) / 4;                 // 4 waves (tiles) per 256-thr block
    node_proj_kernel<<<nblocks, 256, 0, stream>>>(x, w1, b1, ytab, N, ntiles);

    long long octs = ((long long)E + 7) / 8;
    long long tthreads = octs * 8;
    int eblocks = (int)((tthreads + 255) / 256);
    edge_kernel<<<eblocks, 256, 0, stream>>>(ei, ytab, w2, b2, out, E);
}